// Round 4
// baseline (103.453 us; speedup 1.0000x reference)
//
#include <hip/hip_runtime.h>
#include <hip/hip_bf16.h>

#define D_NODE 80
#define EDGE_ITERS 8   // 32-edge tiles per wave per launch

typedef __attribute__((ext_vector_type(8))) short short8;
typedef __attribute__((ext_vector_type(16))) float f32x16;

__device__ __forceinline__ float bf16lo(unsigned u) {
    return __uint_as_float(u << 16);
}
__device__ __forceinline__ float bf16hi(unsigned u) {
    return __uint_as_float(u & 0xffff0000u);
}
__device__ __forceinline__ unsigned packbf2(float a, float b) {
    __hip_bfloat162 h = __float22bfloat162_rn(make_float2(a, b));
    union { __hip_bfloat162 h2; unsigned u; } cv; cv.h2 = h;
    return cv.u;   // low 16 bits = a, high = b
}
__device__ __forceinline__ short f2bf(float f) {
    __hip_bfloat16 h = __float2bfloat16(f);
    union { __hip_bfloat16 h1; short s; } cv; cv.h1 = h;
    return cv.s;
}

// Kernel 1: per-node projection, bf16 outputs. One thread per node, both
// halves. W1/b1 read with wave-uniform indices -> scalar loads (SGPR
// broadcast), zero LDS. acc: 64 f32 VGPRs, no launch-bounds squeeze.
// PS[n][j] = x[n] @ W1[0:80][j]
// PD[n][j] = x[n] @ W1[81:161][j] + b1[j] + W1[80][j]
__global__ __launch_bounds__(256) void proj_kernel(
    const float* __restrict__ X, const float* __restrict__ W1,
    const float* __restrict__ b1,
    unsigned short* __restrict__ PS, unsigned short* __restrict__ PD, int N)
{
    const int n  = blockIdx.x * 256 + threadIdx.x;
    const int nc = (n < N) ? n : 0;

    float accS[32], accD[32];
#pragma unroll
    for (int j4 = 0; j4 < 8; ++j4) {
        float4 bb = *(const float4*)(b1 + j4 * 4);            // uniform -> s_load
        float4 wc = *(const float4*)(W1 + 80 * 32 + j4 * 4);  // uniform -> s_load
        accS[4*j4+0] = 0.f; accS[4*j4+1] = 0.f;
        accS[4*j4+2] = 0.f; accS[4*j4+3] = 0.f;
        accD[4*j4+0] = bb.x + wc.x; accD[4*j4+1] = bb.y + wc.y;
        accD[4*j4+2] = bb.z + wc.z; accD[4*j4+3] = bb.w + wc.w;
    }

    const float4* x4 = (const float4*)(X + (size_t)nc * D_NODE);
#pragma unroll 2
    for (int k4 = 0; k4 < D_NODE / 4; ++k4) {
        float4 xv = x4[k4];
        float xs[4] = {xv.x, xv.y, xv.z, xv.w};
#pragma unroll
        for (int kk = 0; kk < 4; ++kk) {
            int k = k4 * 4 + kk;
            float xk = xs[kk];
            const float4* wS = (const float4*)(W1 + k * 32);          // uniform
            const float4* wD = (const float4*)(W1 + (81 + k) * 32);   // uniform
#pragma unroll
            for (int j4 = 0; j4 < 8; ++j4) {
                float4 ws = wS[j4];
                float4 wd = wD[j4];
                accS[4*j4+0] += xk * ws.x; accS[4*j4+1] += xk * ws.y;
                accS[4*j4+2] += xk * ws.z; accS[4*j4+3] += xk * ws.w;
                accD[4*j4+0] += xk * wd.x; accD[4*j4+1] += xk * wd.y;
                accD[4*j4+2] += xk * wd.z; accD[4*j4+3] += xk * wd.w;
            }
        }
    }

    if (n >= N) return;
    uint4* os = (uint4*)(PS + (size_t)n * 32);
    uint4* od = (uint4*)(PD + (size_t)n * 32);
#pragma unroll
    for (int q = 0; q < 4; ++q) {
        os[q] = make_uint4(packbf2(accS[8*q+0], accS[8*q+1]),
                           packbf2(accS[8*q+2], accS[8*q+3]),
                           packbf2(accS[8*q+4], accS[8*q+5]),
                           packbf2(accS[8*q+6], accS[8*q+7]));
        od[q] = make_uint4(packbf2(accD[8*q+0], accD[8*q+1]),
                           packbf2(accD[8*q+2], accD[8*q+3]),
                           packbf2(accD[8*q+4], accD[8*q+5]),
                           packbf2(accD[8*q+6], accD[8*q+7]));
    }
}

// Kernel 2: 32 edges per wave-iteration via mfma_f32_32x32x16_bf16.
// A = W2 (all 32 output feats on M), B = h1 tile (32 edges on N), 2 k-steps.
// Slot bijection k = (lane>>5)*8 + j used consistently for A and B.
// C/D: col = lane&31 (edge), row = (r&3) + 8*(r>>2) + 4*(lane>>5).
__global__ __launch_bounds__(256) void edge_kernel(
    const int* __restrict__ ei,
    const unsigned short* __restrict__ PS, const unsigned short* __restrict__ PD,
    const float* __restrict__ W2, const float* __restrict__ b2,
    const float* __restrict__ W3, const float* __restrict__ b3,
    float* __restrict__ out, int E)
{
    const int tid  = threadIdx.x;
    const int wave = tid >> 6;
    const int lane = tid & 63;
    const int n    = lane & 31;   // edge-in-tile (B col / C col)
    const int hi   = lane >> 5;   // k-slot group

    // A fragments: step t, slot j <-> k = t*16 + hi*8 + j; A[m=n][k] = W2[k][m]
    short8 Wa0, Wa1;
#pragma unroll
    for (int j = 0; j < 8; ++j) {
        int k0 = hi * 8 + j;
        Wa0[j] = f2bf(W2[k0 * 32 + n]);
        Wa1[j] = f2bf(W2[(16 + k0) * 32 + n]);
    }
    // per-lane constants for the 16 C-rows this lane owns (packed bf16 pairs)
    unsigned b2p[8], w3p[16];
#pragma unroll
    for (int r = 0; r < 16; ++r) {
        int row = (r & 3) + 8 * (r >> 2) + 4 * hi;
        w3p[r] = packbf2(W3[row * 2 + 0], W3[row * 2 + 1]);
        if ((r & 1) == 0) {
            int row2 = ((r + 1) & 3) + 8 * ((r + 1) >> 2) + 4 * hi;
            b2p[r >> 1] = packbf2(b2[row], b2[row2]);
        }
    }
    const float b30 = b3[0], b31 = b3[1];

    const long base = ((long)blockIdx.x * 4 + wave) * (32 * EDGE_ITERS);

    // hoist all index loads (all in flight immediately)
    int sIdx[EDGE_ITERS], dIdx[EDGE_ITERS];
#pragma unroll
    for (int it = 0; it < EDGE_ITERS; ++it) {
        long e = base + (long)it * 32 + n;
        int ec = (e < E) ? (int)e : 0;
        sIdx[it] = ei[ec];
        dIdx[it] = ei[(size_t)E + ec];
    }

    // gather: lane reads 16B at elem offset t*16 + hi*8 of each 64B row
    uint4 av0 = *(const uint4*)(PS + (size_t)sIdx[0] * 32 + hi * 8);
    uint4 av1 = *(const uint4*)(PS + (size_t)sIdx[0] * 32 + 16 + hi * 8);
    uint4 bv0 = *(const uint4*)(PD + (size_t)dIdx[0] * 32 + hi * 8);
    uint4 bv1 = *(const uint4*)(PD + (size_t)dIdx[0] * 32 + 16 + hi * 8);

#pragma unroll
    for (int it = 0; it < EDGE_ITERS; ++it) {
        uint4 pav0, pav1, pbv0, pbv1;
        if (it + 1 < EDGE_ITERS) {   // prefetch next tile's rows
            pav0 = *(const uint4*)(PS + (size_t)sIdx[it+1] * 32 + hi * 8);
            pav1 = *(const uint4*)(PS + (size_t)sIdx[it+1] * 32 + 16 + hi * 8);
            pbv0 = *(const uint4*)(PD + (size_t)dIdx[it+1] * 32 + hi * 8);
            pbv1 = *(const uint4*)(PD + (size_t)dIdx[it+1] * 32 + 16 + hi * 8);
        }

        union { uint4 u; short8 s8; } B0, B1;
        B0.u.x = packbf2(fmaxf(bf16lo(av0.x) + bf16lo(bv0.x), 0.f),
                         fmaxf(bf16hi(av0.x) + bf16hi(bv0.x), 0.f));
        B0.u.y = packbf2(fmaxf(bf16lo(av0.y) + bf16lo(bv0.y), 0.f),
                         fmaxf(bf16hi(av0.y) + bf16hi(bv0.y), 0.f));
        B0.u.z = packbf2(fmaxf(bf16lo(av0.z) + bf16lo(bv0.z), 0.f),
                         fmaxf(bf16hi(av0.z) + bf16hi(bv0.z), 0.f));
        B0.u.w = packbf2(fmaxf(bf16lo(av0.w) + bf16lo(bv0.w), 0.f),
                         fmaxf(bf16hi(av0.w) + bf16hi(bv0.w), 0.f));
        B1.u.x = packbf2(fmaxf(bf16lo(av1.x) + bf16lo(bv1.x), 0.f),
                         fmaxf(bf16hi(av1.x) + bf16hi(bv1.x), 0.f));
        B1.u.y = packbf2(fmaxf(bf16lo(av1.y) + bf16lo(bv1.y), 0.f),
                         fmaxf(bf16hi(av1.y) + bf16hi(bv1.y), 0.f));
        B1.u.z = packbf2(fmaxf(bf16lo(av1.z) + bf16lo(bv1.z), 0.f),
                         fmaxf(bf16hi(av1.z) + bf16hi(bv1.z), 0.f));
        B1.u.w = packbf2(fmaxf(bf16lo(av1.w) + bf16lo(bv1.w), 0.f),
                         fmaxf(bf16hi(av1.w) + bf16hi(bv1.w), 0.f));

        f32x16 c;
#pragma unroll
        for (int q = 0; q < 8; ++q) {
            c[2*q]   = bf16lo(b2p[q]);
            c[2*q+1] = bf16hi(b2p[q]);
        }
        c = __builtin_amdgcn_mfma_f32_32x32x16_bf16(Wa0, B0.s8, c, 0, 0, 0);
        c = __builtin_amdgcn_mfma_f32_32x32x16_bf16(Wa1, B1.s8, c, 0, 0, 0);

        float p0 = 0.f, p1 = 0.f;
#pragma unroll
        for (int r = 0; r < 16; ++r) {
            float h = fmaxf(c[r], 0.f);
            p0 += h * bf16lo(w3p[r]);
            p1 += h * bf16hi(w3p[r]);
        }
        p0 += __shfl_xor(p0, 32, 64);
        p1 += __shfl_xor(p1, 32, 64);

        if (hi == 0) {
            long eo = base + (long)it * 32 + n;
            if (eo < E) {
                float l0 = p0 + b30;
                float l1 = p1 + b31;
                float mm = fmaxf(l0, l1);
                float z  = __expf(l0 - mm) + __expf(l1 - mm);
                float lse = mm + __logf(z);
                *(float2*)(out + 2 * eo) = make_float2(l0 - lse, l1 - lse);
            }
        }
        av0 = pav0; av1 = pav1; bv0 = pbv0; bv1 = pbv1;
    }
}

extern "C" void kernel_launch(void* const* d_in, const int* in_sizes, int n_in,
                              void* d_out, int out_size, void* d_ws, size_t ws_size,
                              hipStream_t stream) {
    const float* X  = (const float*)d_in[0];
    const int*   ei = (const int*)d_in[1];
    const float* W1 = (const float*)d_in[2];
    const float* b1 = (const float*)d_in[3];
    const float* W2 = (const float*)d_in[4];
    const float* b2 = (const float*)d_in[5];
    const float* W3 = (const float*)d_in[6];
    const float* b3 = (const float*)d_in[7];
    float* out = (float*)d_out;

    int N = in_sizes[0] / D_NODE;   // 100000
    int E = in_sizes[1] / 2;        // 1600000

    unsigned short* PS = (unsigned short*)d_ws;            // N*32 bf16 = 6.4 MB
    unsigned short* PD = PS + (size_t)N * 32;              // N*32 bf16 = 6.4 MB

    proj_kernel<<<(N + 255) / 256, 256, 0, stream>>>(X, W1, b1, PS, PD, N);

    int edges_per_block = 4 * 32 * EDGE_ITERS;             // 1024
    int nblk = (E + edges_per_block - 1) / edges_per_block;
    edge_kernel<<<nblk, 256, 0, stream>>>(ei, PS, PD, W2, b2, W3, b3, out, E);
}

// Round 5
// 67.105 us; speedup vs baseline: 1.5417x; 1.5417x over previous
//
#include <hip/hip_runtime.h>
#include <hip/hip_bf16.h>

#define D_NODE 80
#define EDGE_ITERS 8   // 32-edge tiles per wave per launch

typedef __attribute__((ext_vector_type(8))) short short8;
typedef __attribute__((ext_vector_type(16))) float f32x16;

__device__ __forceinline__ float bf16lo(unsigned u) {
    return __uint_as_float(u << 16);
}
__device__ __forceinline__ float bf16hi(unsigned u) {
    return __uint_as_float(u & 0xffff0000u);
}
__device__ __forceinline__ unsigned packbf2(float a, float b) {
    __hip_bfloat162 h = __float22bfloat162_rn(make_float2(a, b));
    union { __hip_bfloat162 h2; unsigned u; } cv; cv.h2 = h;
    return cv.u;   // low 16 bits = a, high = b
}
__device__ __forceinline__ short f2bf(float f) {
    __hip_bfloat16 h = __float2bfloat16(f);
    union { __hip_bfloat16 h1; short s; } cv; cv.h1 = h;
    return cv.s;
}

// Kernel 1: per-node projection as MFMA GEMM.
// A = W1 columns (feats on M, held in VGPR frags for the whole kernel),
// B = X tile (32 nodes on N), K=80 in 5 steps of 16.
// cs = X @ W1[0:80]            -> PS
// cd = X @ W1[81:161] + (b1 + W1[80]) folded into C-init -> PD
// C/D layout: col = lane&31 (node), row(feat) = (r&3)+8*(r>>2)+4*(lane>>5).
__global__ __launch_bounds__(256) void proj_kernel(
    const float* __restrict__ X, const float* __restrict__ W1,
    const float* __restrict__ b1,
    unsigned short* __restrict__ PS, unsigned short* __restrict__ PD, int N)
{
    const int lane = threadIdx.x & 63;
    const int wave = threadIdx.x >> 6;
    const int n    = lane & 31;   // node-in-tile (B/C col) ; feat (A row) for W loads
    const int hi   = lane >> 5;   // k-slot group

    // W fragments, loaded once per wave (coalesced: lanes 0..31 read a 128B row)
    short8 Ws[5], Wd[5];
#pragma unroll
    for (int s = 0; s < 5; ++s) {
#pragma unroll
        for (int j = 0; j < 8; ++j) {
            int k = s * 16 + hi * 8 + j;
            Ws[s][j] = f2bf(W1[k * 32 + n]);
            Wd[s][j] = f2bf(W1[(81 + k) * 32 + n]);
        }
    }
    // C-init for PD: b1[feat] + W1[80][feat]
    float cdInit[16];
#pragma unroll
    for (int r = 0; r < 16; ++r) {
        int f = (r & 3) + 8 * (r >> 2) + 4 * hi;
        cdInit[r] = b1[f] + W1[80 * 32 + f];
    }

    const int tiles = N / 32;   // 3125 exactly for N=100000
    for (int tile = blockIdx.x * 4 + wave; tile < tiles; tile += gridDim.x * 4) {
        const int node = tile * 32 + n;
        const float4* xrow = (const float4*)(X + (size_t)node * D_NODE + hi * 8);

        f32x16 cs, cd;
#pragma unroll
        for (int r = 0; r < 16; ++r) { cs[r] = 0.0f; cd[r] = cdInit[r]; }

#pragma unroll
        for (int s = 0; s < 5; ++s) {
            float4 xa = xrow[s * 4];       // elems s*16 + hi*8 + 0..3
            float4 xb = xrow[s * 4 + 1];   // elems s*16 + hi*8 + 4..7
            union { uint4 u; short8 s8; } Bx;
            Bx.u.x = packbf2(xa.x, xa.y);
            Bx.u.y = packbf2(xa.z, xa.w);
            Bx.u.z = packbf2(xb.x, xb.y);
            Bx.u.w = packbf2(xb.z, xb.w);
            cs = __builtin_amdgcn_mfma_f32_32x32x16_bf16(Ws[s], Bx.s8, cs, 0, 0, 0);
            cd = __builtin_amdgcn_mfma_f32_32x32x16_bf16(Wd[s], Bx.s8, cd, 0, 0, 0);
        }

        // store: reg quad q = feats 8*q + 4*hi .. +3 of this lane's node
        unsigned short* psr = PS + (size_t)node * 32 + hi * 4;
        unsigned short* pdr = PD + (size_t)node * 32 + hi * 4;
#pragma unroll
        for (int q = 0; q < 4; ++q) {
            uint2 vs = make_uint2(packbf2(cs[4*q+0], cs[4*q+1]),
                                  packbf2(cs[4*q+2], cs[4*q+3]));
            uint2 vd = make_uint2(packbf2(cd[4*q+0], cd[4*q+1]),
                                  packbf2(cd[4*q+2], cd[4*q+3]));
            *(uint2*)(psr + q * 8) = vs;
            *(uint2*)(pdr + q * 8) = vd;
        }
    }
}

// Kernel 2: 32 edges per wave-iteration via mfma_f32_32x32x16_bf16.
// A = W2 (all 32 output feats on M), B = h1 tile (32 edges on N), 2 k-steps.
// Slot bijection k = (lane>>5)*8 + j used consistently for A and B.
// C/D: col = lane&31 (edge), row = (r&3) + 8*(r>>2) + 4*(lane>>5).
__global__ __launch_bounds__(256) void edge_kernel(
    const int* __restrict__ ei,
    const unsigned short* __restrict__ PS, const unsigned short* __restrict__ PD,
    const float* __restrict__ W2, const float* __restrict__ b2,
    const float* __restrict__ W3, const float* __restrict__ b3,
    float* __restrict__ out, int E)
{
    const int tid  = threadIdx.x;
    const int wave = tid >> 6;
    const int lane = tid & 63;
    const int n    = lane & 31;   // edge-in-tile (B col / C col)
    const int hi   = lane >> 5;   // k-slot group

    // A fragments: step t, slot j <-> k = t*16 + hi*8 + j; A[m=n][k] = W2[k][m]
    short8 Wa0, Wa1;
#pragma unroll
    for (int j = 0; j < 8; ++j) {
        int k0 = hi * 8 + j;
        Wa0[j] = f2bf(W2[k0 * 32 + n]);
        Wa1[j] = f2bf(W2[(16 + k0) * 32 + n]);
    }
    // per-lane constants for the 16 C-rows this lane owns (packed bf16 pairs)
    unsigned b2p[8], w3p[16];
#pragma unroll
    for (int r = 0; r < 16; ++r) {
        int row = (r & 3) + 8 * (r >> 2) + 4 * hi;
        w3p[r] = packbf2(W3[row * 2 + 0], W3[row * 2 + 1]);
        if ((r & 1) == 0) {
            int row2 = ((r + 1) & 3) + 8 * ((r + 1) >> 2) + 4 * hi;
            b2p[r >> 1] = packbf2(b2[row], b2[row2]);
        }
    }
    const float b30 = b3[0], b31 = b3[1];

    const long base = ((long)blockIdx.x * 4 + wave) * (32 * EDGE_ITERS);

    // hoist all index loads (all in flight immediately)
    int sIdx[EDGE_ITERS], dIdx[EDGE_ITERS];
#pragma unroll
    for (int it = 0; it < EDGE_ITERS; ++it) {
        long e = base + (long)it * 32 + n;
        int ec = (e < E) ? (int)e : 0;
        sIdx[it] = ei[ec];
        dIdx[it] = ei[(size_t)E + ec];
    }

    // gather: lane reads 16B at elem offset t*16 + hi*8 of each 64B row
    uint4 av0 = *(const uint4*)(PS + (size_t)sIdx[0] * 32 + hi * 8);
    uint4 av1 = *(const uint4*)(PS + (size_t)sIdx[0] * 32 + 16 + hi * 8);
    uint4 bv0 = *(const uint4*)(PD + (size_t)dIdx[0] * 32 + hi * 8);
    uint4 bv1 = *(const uint4*)(PD + (size_t)dIdx[0] * 32 + 16 + hi * 8);

#pragma unroll
    for (int it = 0; it < EDGE_ITERS; ++it) {
        uint4 pav0, pav1, pbv0, pbv1;
        if (it + 1 < EDGE_ITERS) {   // prefetch next tile's rows
            pav0 = *(const uint4*)(PS + (size_t)sIdx[it+1] * 32 + hi * 8);
            pav1 = *(const uint4*)(PS + (size_t)sIdx[it+1] * 32 + 16 + hi * 8);
            pbv0 = *(const uint4*)(PD + (size_t)dIdx[it+1] * 32 + hi * 8);
            pbv1 = *(const uint4*)(PD + (size_t)dIdx[it+1] * 32 + 16 + hi * 8);
        }

        union { uint4 u; short8 s8; } B0, B1;
        B0.u.x = packbf2(fmaxf(bf16lo(av0.x) + bf16lo(bv0.x), 0.f),
                         fmaxf(bf16hi(av0.x) + bf16hi(bv0.x), 0.f));
        B0.u.y = packbf2(fmaxf(bf16lo(av0.y) + bf16lo(bv0.y), 0.f),
                         fmaxf(bf16hi(av0.y) + bf16hi(bv0.y), 0.f));
        B0.u.z = packbf2(fmaxf(bf16lo(av0.z) + bf16lo(bv0.z), 0.f),
                         fmaxf(bf16hi(av0.z) + bf16hi(bv0.z), 0.f));
        B0.u.w = packbf2(fmaxf(bf16lo(av0.w) + bf16lo(bv0.w), 0.f),
                         fmaxf(bf16hi(av0.w) + bf16hi(bv0.w), 0.f));
        B1.u.x = packbf2(fmaxf(bf16lo(av1.x) + bf16lo(bv1.x), 0.f),
                         fmaxf(bf16hi(av1.x) + bf16hi(bv1.x), 0.f));
        B1.u.y = packbf2(fmaxf(bf16lo(av1.y) + bf16lo(bv1.y), 0.f),
                         fmaxf(bf16hi(av1.y) + bf16hi(bv1.y), 0.f));
        B1.u.z = packbf2(fmaxf(bf16lo(av1.z) + bf16lo(bv1.z), 0.f),
                         fmaxf(bf16hi(av1.z) + bf16hi(bv1.z), 0.f));
        B1.u.w = packbf2(fmaxf(bf16lo(av1.w) + bf16lo(bv1.w), 0.f),
                         fmaxf(bf16hi(av1.w) + bf16hi(bv1.w), 0.f));

        f32x16 c;
#pragma unroll
        for (int q = 0; q < 8; ++q) {
            c[2*q]   = bf16lo(b2p[q]);
            c[2*q+1] = bf16hi(b2p[q]);
        }
        c = __builtin_amdgcn_mfma_f32_32x32x16_bf16(Wa0, B0.s8, c, 0, 0, 0);
        c = __builtin_amdgcn_mfma_f32_32x32x16_bf16(Wa1, B1.s8, c, 0, 0, 0);

        float p0 = 0.f, p1 = 0.f;
#pragma unroll
        for (int r = 0; r < 16; ++r) {
            float h = fmaxf(c[r], 0.f);
            p0 += h * bf16lo(w3p[r]);
            p1 += h * bf16hi(w3p[r]);
        }
        p0 += __shfl_xor(p0, 32, 64);
        p1 += __shfl_xor(p1, 32, 64);

        if (hi == 0) {
            long eo = base + (long)it * 32 + n;
            if (eo < E) {
                float l0 = p0 + b30;
                float l1 = p1 + b31;
                float mm = fmaxf(l0, l1);
                float z  = __expf(l0 - mm) + __expf(l1 - mm);
                float lse = mm + __logf(z);
                *(float2*)(out + 2 * eo) = make_float2(l0 - lse, l1 - lse);
            }
        }
        av0 = pav0; av1 = pav1; bv0 = pbv0; bv1 = pbv1;
    }
}

extern "C" void kernel_launch(void* const* d_in, const int* in_sizes, int n_in,
                              void* d_out, int out_size, void* d_ws, size_t ws_size,
                              hipStream_t stream) {
    const float* X  = (const float*)d_in[0];
    const int*   ei = (const int*)d_in[1];
    const float* W1 = (const float*)d_in[2];
    const float* b1 = (const float*)d_in[3];
    const float* W2 = (const float*)d_in[4];
    const float* b2 = (const float*)d_in[5];
    const float* W3 = (const float*)d_in[6];
    const float* b3 = (const float*)d_in[7];
    float* out = (float*)d_out;

    int N = in_sizes[0] / D_NODE;   // 100000
    int E = in_sizes[1] / 2;        // 1600000

    unsigned short* PS = (unsigned short*)d_ws;            // N*32 bf16 = 6.4 MB
    unsigned short* PD = PS + (size_t)N * 32;              // N*32 bf16 = 6.4 MB

    proj_kernel<<<256, 256, 0, stream>>>(X, W1, b1, PS, PD, N);

    int edges_per_block = 4 * 32 * EDGE_ITERS;             // 1024
    int nblk = (E + edges_per_block - 1) / edges_per_block;
    edge_kernel<<<nblk, 256, 0, stream>>>(ei, PS, PD, W2, b2, W3, b3, out, E);
}

// Round 6
// 66.662 us; speedup vs baseline: 1.5519x; 1.0066x over previous
//
#include <hip/hip_runtime.h>
#include <hip/hip_bf16.h>

#define D_NODE 80
#define EDGE_ITERS 4   // 32-edge tiles per wave; all gathers issued upfront

typedef __attribute__((ext_vector_type(8))) short short8;
typedef __attribute__((ext_vector_type(16))) float f32x16;

__device__ __forceinline__ float bf16lo(unsigned u) {
    return __uint_as_float(u << 16);
}
__device__ __forceinline__ float bf16hi(unsigned u) {
    return __uint_as_float(u & 0xffff0000u);
}
__device__ __forceinline__ unsigned packbf2(float a, float b) {
    __hip_bfloat162 h = __float22bfloat162_rn(make_float2(a, b));
    union { __hip_bfloat162 h2; unsigned u; } cv; cv.h2 = h;
    return cv.u;   // low 16 bits = a, high = b
}
__device__ __forceinline__ short f2bf(float f) {
    __hip_bfloat16 h = __float2bfloat16(f);
    union { __hip_bfloat16 h1; short s; } cv; cv.h1 = h;
    return cv.s;
}

// Kernel 1: per-node projection as MFMA GEMM.
// A = W1 columns (feats on M, VGPR-resident), B = X tile (32 nodes on N),
// K=80 in 5 steps. cs -> PS ; cd (+ b1 + W1[80] folded) -> PD.
// C/D layout: col = lane&31 (node), row(feat) = (r&3)+8*(r>>2)+4*(lane>>5).
__global__ __launch_bounds__(256) void proj_kernel(
    const float* __restrict__ X, const float* __restrict__ W1,
    const float* __restrict__ b1,
    unsigned short* __restrict__ PS, unsigned short* __restrict__ PD, int N)
{
    const int lane = threadIdx.x & 63;
    const int wave = threadIdx.x >> 6;
    const int n    = lane & 31;   // node-in-tile (B/C col) ; feat (A row) for W loads
    const int hi   = lane >> 5;   // k-slot group

    // W fragments, loaded once per wave (coalesced: lanes 0..31 read a 128B row)
    short8 Ws[5], Wd[5];
#pragma unroll
    for (int s = 0; s < 5; ++s) {
#pragma unroll
        for (int j = 0; j < 8; ++j) {
            int k = s * 16 + hi * 8 + j;
            Ws[s][j] = f2bf(W1[k * 32 + n]);
            Wd[s][j] = f2bf(W1[(81 + k) * 32 + n]);
        }
    }
    // C-init for PD: b1[feat] + W1[80][feat]
    float cdInit[16];
#pragma unroll
    for (int r = 0; r < 16; ++r) {
        int f = (r & 3) + 8 * (r >> 2) + 4 * hi;
        cdInit[r] = b1[f] + W1[80 * 32 + f];
    }

    const int tiles = N / 32;   // 3125 exactly for N=100000
    for (int tile = blockIdx.x * 4 + wave; tile < tiles; tile += gridDim.x * 4) {
        const int node = tile * 32 + n;
        const float4* xrow = (const float4*)(X + (size_t)node * D_NODE + hi * 8);

        f32x16 cs, cd;
#pragma unroll
        for (int r = 0; r < 16; ++r) { cs[r] = 0.0f; cd[r] = cdInit[r]; }

#pragma unroll
        for (int s = 0; s < 5; ++s) {
            float4 xa = xrow[s * 4];       // elems s*16 + hi*8 + 0..3
            float4 xb = xrow[s * 4 + 1];   // elems s*16 + hi*8 + 4..7
            union { uint4 u; short8 s8; } Bx;
            Bx.u.x = packbf2(xa.x, xa.y);
            Bx.u.y = packbf2(xa.z, xa.w);
            Bx.u.z = packbf2(xb.x, xb.y);
            Bx.u.w = packbf2(xb.z, xb.w);
            cs = __builtin_amdgcn_mfma_f32_32x32x16_bf16(Ws[s], Bx.s8, cs, 0, 0, 0);
            cd = __builtin_amdgcn_mfma_f32_32x32x16_bf16(Wd[s], Bx.s8, cd, 0, 0, 0);
        }

        // store: reg quad q = feats 8*q + 4*hi .. +3 of this lane's node
        unsigned short* psr = PS + (size_t)node * 32 + hi * 4;
        unsigned short* pdr = PD + (size_t)node * 32 + hi * 4;
#pragma unroll
        for (int q = 0; q < 4; ++q) {
            uint2 vs = make_uint2(packbf2(cs[4*q+0], cs[4*q+1]),
                                  packbf2(cs[4*q+2], cs[4*q+3]));
            uint2 vd = make_uint2(packbf2(cd[4*q+0], cd[4*q+1]),
                                  packbf2(cd[4*q+2], cd[4*q+3]));
            *(uint2*)(psr + q * 8) = vs;
            *(uint2*)(pdr + q * 8) = vd;
        }
    }
}

// Kernel 2: 32 edges per wave-iteration via mfma_f32_32x32x16_bf16.
// A = W2 (feats on M), B = h1 tile (32 edges on N), 2 k-steps.
// ALL gathers for EDGE_ITERS tiles issued upfront -> 16 loads in flight/wave.
__global__ __launch_bounds__(256) void edge_kernel(
    const int* __restrict__ ei,
    const unsigned short* __restrict__ PS, const unsigned short* __restrict__ PD,
    const float* __restrict__ W2, const float* __restrict__ b2,
    const float* __restrict__ W3, const float* __restrict__ b3,
    float* __restrict__ out, int E)
{
    const int tid  = threadIdx.x;
    const int wave = tid >> 6;
    const int lane = tid & 63;
    const int n    = lane & 31;   // edge-in-tile (B col / C col)
    const int hi   = lane >> 5;   // k-slot group

    // A fragments: step t, slot j <-> k = t*16 + hi*8 + j; A[m=n][k] = W2[k][m]
    short8 Wa0, Wa1;
#pragma unroll
    for (int j = 0; j < 8; ++j) {
        int k0 = hi * 8 + j;
        Wa0[j] = f2bf(W2[k0 * 32 + n]);
        Wa1[j] = f2bf(W2[(16 + k0) * 32 + n]);
    }
    // per-lane constants for the 16 C-rows this lane owns (packed bf16 pairs)
    unsigned b2p[8], w3p[16];
#pragma unroll
    for (int r = 0; r < 16; ++r) {
        int row = (r & 3) + 8 * (r >> 2) + 4 * hi;
        w3p[r] = packbf2(W3[row * 2 + 0], W3[row * 2 + 1]);
        if ((r & 1) == 0) {
            int row2 = ((r + 1) & 3) + 8 * ((r + 1) >> 2) + 4 * hi;
            b2p[r >> 1] = packbf2(b2[row], b2[row2]);
        }
    }
    const float b30 = b3[0], b31 = b3[1];

    const long base = ((long)blockIdx.x * 4 + wave) * (32 * EDGE_ITERS);

    // index loads: all in flight immediately
    int sIdx[EDGE_ITERS], dIdx[EDGE_ITERS];
#pragma unroll
    for (int it = 0; it < EDGE_ITERS; ++it) {
        long e = base + (long)it * 32 + n;
        int ec = (e < E) ? (int)e : 0;
        sIdx[it] = ei[ec];
        dIdx[it] = ei[(size_t)E + ec];
    }

    // row gathers for ALL tiles issued upfront (16 x 16B in flight per lane)
    uint4 av0[EDGE_ITERS], av1[EDGE_ITERS], bv0[EDGE_ITERS], bv1[EDGE_ITERS];
#pragma unroll
    for (int it = 0; it < EDGE_ITERS; ++it) {
        av0[it] = *(const uint4*)(PS + (size_t)sIdx[it] * 32 + hi * 8);
        av1[it] = *(const uint4*)(PS + (size_t)sIdx[it] * 32 + 16 + hi * 8);
        bv0[it] = *(const uint4*)(PD + (size_t)dIdx[it] * 32 + hi * 8);
        bv1[it] = *(const uint4*)(PD + (size_t)dIdx[it] * 32 + 16 + hi * 8);
    }

#pragma unroll
    for (int it = 0; it < EDGE_ITERS; ++it) {
        union { uint4 u; short8 s8; } B0, B1;
        B0.u.x = packbf2(fmaxf(bf16lo(av0[it].x) + bf16lo(bv0[it].x), 0.f),
                         fmaxf(bf16hi(av0[it].x) + bf16hi(bv0[it].x), 0.f));
        B0.u.y = packbf2(fmaxf(bf16lo(av0[it].y) + bf16lo(bv0[it].y), 0.f),
                         fmaxf(bf16hi(av0[it].y) + bf16hi(bv0[it].y), 0.f));
        B0.u.z = packbf2(fmaxf(bf16lo(av0[it].z) + bf16lo(bv0[it].z), 0.f),
                         fmaxf(bf16hi(av0[it].z) + bf16hi(bv0[it].z), 0.f));
        B0.u.w = packbf2(fmaxf(bf16lo(av0[it].w) + bf16lo(bv0[it].w), 0.f),
                         fmaxf(bf16hi(av0[it].w) + bf16hi(bv0[it].w), 0.f));
        B1.u.x = packbf2(fmaxf(bf16lo(av1[it].x) + bf16lo(bv1[it].x), 0.f),
                         fmaxf(bf16hi(av1[it].x) + bf16hi(bv1[it].x), 0.f));
        B1.u.y = packbf2(fmaxf(bf16lo(av1[it].y) + bf16lo(bv1[it].y), 0.f),
                         fmaxf(bf16hi(av1[it].y) + bf16hi(bv1[it].y), 0.f));
        B1.u.z = packbf2(fmaxf(bf16lo(av1[it].z) + bf16lo(bv1[it].z), 0.f),
                         fmaxf(bf16hi(av1[it].z) + bf16hi(bv1[it].z), 0.f));
        B1.u.w = packbf2(fmaxf(bf16lo(av1[it].w) + bf16lo(bv1[it].w), 0.f),
                         fmaxf(bf16hi(av1[it].w) + bf16hi(bv1[it].w), 0.f));

        f32x16 c;
#pragma unroll
        for (int q = 0; q < 8; ++q) {
            c[2*q]   = bf16lo(b2p[q]);
            c[2*q+1] = bf16hi(b2p[q]);
        }
        c = __builtin_amdgcn_mfma_f32_32x32x16_bf16(Wa0, B0.s8, c, 0, 0, 0);
        c = __builtin_amdgcn_mfma_f32_32x32x16_bf16(Wa1, B1.s8, c, 0, 0, 0);

        float p0 = 0.f, p1 = 0.f;
#pragma unroll
        for (int r = 0; r < 16; ++r) {
            float h = fmaxf(c[r], 0.f);
            p0 += h * bf16lo(w3p[r]);
            p1 += h * bf16hi(w3p[r]);
        }
        p0 += __shfl_xor(p0, 32, 64);
        p1 += __shfl_xor(p1, 32, 64);

        if (hi == 0) {
            long eo = base + (long)it * 32 + n;
            if (eo < E) {
                float l0 = p0 + b30;
                float l1 = p1 + b31;
                float mm = fmaxf(l0, l1);
                float z  = __expf(l0 - mm) + __expf(l1 - mm);
                float lse = mm + __logf(z);
                *(float2*)(out + 2 * eo) = make_float2(l0 - lse, l1 - lse);
            }
        }
    }
}

extern "C" void kernel_launch(void* const* d_in, const int* in_sizes, int n_in,
                              void* d_out, int out_size, void* d_ws, size_t ws_size,
                              hipStream_t stream) {
    const float* X  = (const float*)d_in[0];
    const int*   ei = (const int*)d_in[1];
    const float* W1 = (const float*)d_in[2];
    const float* b1 = (const float*)d_in[3];
    const float* W2 = (const float*)d_in[4];
    const float* b2 = (const float*)d_in[5];
    const float* W3 = (const float*)d_in[6];
    const float* b3 = (const float*)d_in[7];
    float* out = (float*)d_out;

    int N = in_sizes[0] / D_NODE;   // 100000
    int E = in_sizes[1] / 2;        // 1600000

    unsigned short* PS = (unsigned short*)d_ws;            // N*32 bf16 = 6.4 MB
    unsigned short* PD = PS + (size_t)N * 32;              // N*32 bf16 = 6.4 MB

    int ptiles = (N / 32 + 3) / 4;                         // 782 blocks, 1 tile/wave
    proj_kernel<<<ptiles, 256, 0, stream>>>(X, W1, b1, PS, PD, N);

    int edges_per_block = 4 * 32 * EDGE_ITERS;             // 512
    int nblk = (E + edges_per_block - 1) / edges_per_block;
    edge_kernel<<<nblk, 256, 0, stream>>>(ei, PS, PD, W2, b2, W3, b3, out, E);
}

// Round 7
// 61.226 us; speedup vs baseline: 1.6897x; 1.0888x over previous
//
#include <hip/hip_runtime.h>
#include <hip/hip_bf16.h>

#define D_NODE 80
#define EDGE_ITERS 2   // 32-edge tiles per wave; all gathers issued upfront

typedef __attribute__((ext_vector_type(8))) short short8;
typedef __attribute__((ext_vector_type(16))) float f32x16;

__device__ __forceinline__ float bf16lo(unsigned u) {
    return __uint_as_float(u << 16);
}
__device__ __forceinline__ float bf16hi(unsigned u) {
    return __uint_as_float(u & 0xffff0000u);
}
__device__ __forceinline__ unsigned packbf2(float a, float b) {
    __hip_bfloat162 h = __float22bfloat162_rn(make_float2(a, b));
    union { __hip_bfloat162 h2; unsigned u; } cv; cv.h2 = h;
    return cv.u;   // low 16 bits = a, high = b
}
__device__ __forceinline__ short f2bf(float f) {
    __hip_bfloat16 h = __float2bfloat16(f);
    union { __hip_bfloat16 h1; short s; } cv; cv.h1 = h;
    return cv.s;
}

// Kernel 1: per-node projection as MFMA GEMM, grid-stride with X prefetch-1.
// A = W1 columns (feats on M, VGPR-resident), B = X tile (32 nodes on N),
// K=80 in 5 steps. cs -> PS ; cd (+ b1 + W1[80] folded) -> PD.
// C/D layout: col = lane&31 (node), row(feat) = (r&3)+8*(r>>2)+4*(lane>>5).
__global__ __launch_bounds__(256) void proj_kernel(
    const float* __restrict__ X, const float* __restrict__ W1,
    const float* __restrict__ b1,
    unsigned short* __restrict__ PS, unsigned short* __restrict__ PD, int N)
{
    const int lane = threadIdx.x & 63;
    const int wave = threadIdx.x >> 6;
    const int n    = lane & 31;   // node-in-tile (B/C col) ; feat (A row) for W loads
    const int hi   = lane >> 5;   // k-slot group

    const int tiles  = N / 32;            // 3125 for N=100000
    const int stride = gridDim.x * 4;
    int tile = blockIdx.x * 4 + wave;
    if (tile >= tiles) return;

    // first tile's X loads issued BEFORE the W-fragment setup (both in flight)
    float4 xc[10];
    {
        const float4* xrow = (const float4*)(X + (size_t)(tile * 32 + n) * D_NODE + hi * 8);
#pragma unroll
        for (int s = 0; s < 5; ++s) { xc[2*s] = xrow[s*4]; xc[2*s+1] = xrow[s*4+1]; }
    }

    // W fragments, loaded once per wave (coalesced: lanes 0..31 read a 128B row)
    short8 Ws[5], Wd[5];
#pragma unroll
    for (int s = 0; s < 5; ++s) {
#pragma unroll
        for (int j = 0; j < 8; ++j) {
            int k = s * 16 + hi * 8 + j;
            Ws[s][j] = f2bf(W1[k * 32 + n]);
            Wd[s][j] = f2bf(W1[(81 + k) * 32 + n]);
        }
    }
    // C-init for PD: b1[feat] + W1[80][feat]
    float cdInit[16];
#pragma unroll
    for (int r = 0; r < 16; ++r) {
        int f = (r & 3) + 8 * (r >> 2) + 4 * hi;
        cdInit[r] = b1[f] + W1[80 * 32 + f];
    }

    while (tile < tiles) {
        const int nt = tile + stride;
        float4 xn[10];
        if (nt < tiles) {   // prefetch next tile's X under this tile's compute
            const float4* xrow = (const float4*)(X + (size_t)(nt * 32 + n) * D_NODE + hi * 8);
#pragma unroll
            for (int s = 0; s < 5; ++s) { xn[2*s] = xrow[s*4]; xn[2*s+1] = xrow[s*4+1]; }
        }

        f32x16 cs, cd;
#pragma unroll
        for (int r = 0; r < 16; ++r) { cs[r] = 0.0f; cd[r] = cdInit[r]; }

#pragma unroll
        for (int s = 0; s < 5; ++s) {
            union { uint4 u; short8 s8; } Bx;
            Bx.u.x = packbf2(xc[2*s].x, xc[2*s].y);
            Bx.u.y = packbf2(xc[2*s].z, xc[2*s].w);
            Bx.u.z = packbf2(xc[2*s+1].x, xc[2*s+1].y);
            Bx.u.w = packbf2(xc[2*s+1].z, xc[2*s+1].w);
            cs = __builtin_amdgcn_mfma_f32_32x32x16_bf16(Ws[s], Bx.s8, cs, 0, 0, 0);
            cd = __builtin_amdgcn_mfma_f32_32x32x16_bf16(Wd[s], Bx.s8, cd, 0, 0, 0);
        }

        const int node = tile * 32 + n;
        unsigned short* psr = PS + (size_t)node * 32 + hi * 4;
        unsigned short* pdr = PD + (size_t)node * 32 + hi * 4;
#pragma unroll
        for (int q = 0; q < 4; ++q) {
            uint2 vs = make_uint2(packbf2(cs[4*q+0], cs[4*q+1]),
                                  packbf2(cs[4*q+2], cs[4*q+3]));
            uint2 vd = make_uint2(packbf2(cd[4*q+0], cd[4*q+1]),
                                  packbf2(cd[4*q+2], cd[4*q+3]));
            *(uint2*)(psr + q * 8) = vs;
            *(uint2*)(pdr + q * 8) = vd;
        }

#pragma unroll
        for (int i = 0; i < 10; ++i) xc[i] = xn[i];
        tile = nt;
    }
}

// Kernel 2: 32 edges per wave-iteration via mfma_f32_32x32x16_bf16.
// A = W2 (feats on M), B = h1 tile (32 edges on N), 2 k-steps.
// EDGE_ITERS=2: 8 upfront gathers = 32 VGPR of data -> compiler can keep
// them in flight (round-6's 16-gather version was sunk; VGPR stayed 76).
__global__ __launch_bounds__(256) void edge_kernel(
    const int* __restrict__ ei,
    const unsigned short* __restrict__ PS, const unsigned short* __restrict__ PD,
    const float* __restrict__ W2, const float* __restrict__ b2,
    const float* __restrict__ W3, const float* __restrict__ b3,
    float* __restrict__ out, int E)
{
    const int tid  = threadIdx.x;
    const int wave = tid >> 6;
    const int lane = tid & 63;
    const int n    = lane & 31;   // edge-in-tile (B col / C col)
    const int hi   = lane >> 5;   // k-slot group

    // A fragments: step t, slot j <-> k = t*16 + hi*8 + j; A[m=n][k] = W2[k][m]
    short8 Wa0, Wa1;
#pragma unroll
    for (int j = 0; j < 8; ++j) {
        int k0 = hi * 8 + j;
        Wa0[j] = f2bf(W2[k0 * 32 + n]);
        Wa1[j] = f2bf(W2[(16 + k0) * 32 + n]);
    }
    // per-lane constants for the 16 C-rows this lane owns (packed bf16 pairs)
    unsigned b2p[8], w3p[16];
#pragma unroll
    for (int r = 0; r < 16; ++r) {
        int row = (r & 3) + 8 * (r >> 2) + 4 * hi;
        w3p[r] = packbf2(W3[row * 2 + 0], W3[row * 2 + 1]);
        if ((r & 1) == 0) {
            int row2 = ((r + 1) & 3) + 8 * ((r + 1) >> 2) + 4 * hi;
            b2p[r >> 1] = packbf2(b2[row], b2[row2]);
        }
    }
    const float b30 = b3[0], b31 = b3[1];

    const long base = ((long)blockIdx.x * 4 + wave) * (32 * EDGE_ITERS);

    // index loads: all in flight immediately
    int sIdx[EDGE_ITERS], dIdx[EDGE_ITERS];
#pragma unroll
    for (int it = 0; it < EDGE_ITERS; ++it) {
        long e = base + (long)it * 32 + n;
        int ec = (e < E) ? (int)e : 0;
        sIdx[it] = ei[ec];
        dIdx[it] = ei[(size_t)E + ec];
    }

    // row gathers for BOTH tiles issued upfront (8 x 16B in flight per lane)
    uint4 av0[EDGE_ITERS], av1[EDGE_ITERS], bv0[EDGE_ITERS], bv1[EDGE_ITERS];
#pragma unroll
    for (int it = 0; it < EDGE_ITERS; ++it) {
        av0[it] = *(const uint4*)(PS + (size_t)sIdx[it] * 32 + hi * 8);
        av1[it] = *(const uint4*)(PS + (size_t)sIdx[it] * 32 + 16 + hi * 8);
        bv0[it] = *(const uint4*)(PD + (size_t)dIdx[it] * 32 + hi * 8);
        bv1[it] = *(const uint4*)(PD + (size_t)dIdx[it] * 32 + 16 + hi * 8);
    }

#pragma unroll
    for (int it = 0; it < EDGE_ITERS; ++it) {
        union { uint4 u; short8 s8; } B0, B1;
        B0.u.x = packbf2(fmaxf(bf16lo(av0[it].x) + bf16lo(bv0[it].x), 0.f),
                         fmaxf(bf16hi(av0[it].x) + bf16hi(bv0[it].x), 0.f));
        B0.u.y = packbf2(fmaxf(bf16lo(av0[it].y) + bf16lo(bv0[it].y), 0.f),
                         fmaxf(bf16hi(av0[it].y) + bf16hi(bv0[it].y), 0.f));
        B0.u.z = packbf2(fmaxf(bf16lo(av0[it].z) + bf16lo(bv0[it].z), 0.f),
                         fmaxf(bf16hi(av0[it].z) + bf16hi(bv0[it].z), 0.f));
        B0.u.w = packbf2(fmaxf(bf16lo(av0[it].w) + bf16lo(bv0[it].w), 0.f),
                         fmaxf(bf16hi(av0[it].w) + bf16hi(bv0[it].w), 0.f));
        B1.u.x = packbf2(fmaxf(bf16lo(av1[it].x) + bf16lo(bv1[it].x), 0.f),
                         fmaxf(bf16hi(av1[it].x) + bf16hi(bv1[it].x), 0.f));
        B1.u.y = packbf2(fmaxf(bf16lo(av1[it].y) + bf16lo(bv1[it].y), 0.f),
                         fmaxf(bf16hi(av1[it].y) + bf16hi(bv1[it].y), 0.f));
        B1.u.z = packbf2(fmaxf(bf16lo(av1[it].z) + bf16lo(bv1[it].z), 0.f),
                         fmaxf(bf16hi(av1[it].z) + bf16hi(bv1[it].z), 0.f));
        B1.u.w = packbf2(fmaxf(bf16lo(av1[it].w) + bf16lo(bv1[it].w), 0.f),
                         fmaxf(bf16hi(av1[it].w) + bf16hi(bv1[it].w), 0.f));

        f32x16 c;
#pragma unroll
        for (int q = 0; q < 8; ++q) {
            c[2*q]   = bf16lo(b2p[q]);
            c[2*q+1] = bf16hi(b2p[q]);
        }
        c = __builtin_amdgcn_mfma_f32_32x32x16_bf16(Wa0, B0.s8, c, 0, 0, 0);
        c = __builtin_amdgcn_mfma_f32_32x32x16_bf16(Wa1, B1.s8, c, 0, 0, 0);

        float p0 = 0.f, p1 = 0.f;
#pragma unroll
        for (int r = 0; r < 16; ++r) {
            float h = fmaxf(c[r], 0.f);
            p0 += h * bf16lo(w3p[r]);
            p1 += h * bf16hi(w3p[r]);
        }
        p0 += __shfl_xor(p0, 32, 64);
        p1 += __shfl_xor(p1, 32, 64);

        if (hi == 0) {
            long eo = base + (long)it * 32 + n;
            if (eo < E) {
                float l0 = p0 + b30;
                float l1 = p1 + b31;
                float mm = fmaxf(l0, l1);
                float z  = __expf(l0 - mm) + __expf(l1 - mm);
                float lse = mm + __logf(z);
                *(float2*)(out + 2 * eo) = make_float2(l0 - lse, l1 - lse);
            }
        }
    }
}

extern "C" void kernel_launch(void* const* d_in, const int* in_sizes, int n_in,
                              void* d_out, int out_size, void* d_ws, size_t ws_size,
                              hipStream_t stream) {
    const float* X  = (const float*)d_in[0];
    const int*   ei = (const int*)d_in[1];
    const float* W1 = (const float*)d_in[2];
    const float* b1 = (const float*)d_in[3];
    const float* W2 = (const float*)d_in[4];
    const float* b2 = (const float*)d_in[5];
    const float* W3 = (const float*)d_in[6];
    const float* b3 = (const float*)d_in[7];
    float* out = (float*)d_out;

    int N = in_sizes[0] / D_NODE;   // 100000
    int E = in_sizes[1] / 2;        // 1600000

    unsigned short* PS = (unsigned short*)d_ws;            // N*32 bf16 = 6.4 MB
    unsigned short* PD = PS + (size_t)N * 32;              // N*32 bf16 = 6.4 MB

    proj_kernel<<<256, 256, 0, stream>>>(X, W1, b1, PS, PD, N);

    int edges_per_block = 4 * 32 * EDGE_ITERS;             // 256
    int nblk = (E + edges_per_block - 1) / edges_per_block; // 6250
    edge_kernel<<<nblk, 256, 0, stream>>>(ei, PS, PD, W2, b2, W3, b3, out, E);
}